// Round 1
// baseline (97.121 us; speedup 1.0000x reference)
//
#include <hip/hip_runtime.h>

// Problem constants
#define Bq   2
#define Lq   2048
#define Hq   8
#define DKq  64
#define BHq  (Bq*Hq)            // 16
#define NQf  (BHq*Lq*DKq)       // 2097152 floats per [B,H,L,64] array
#define NROW (BHq*Lq)           // 32768 rows

// workspace layout (float offsets)
#define OFF_Q  0
#define OFF_K  (NQf)
#define OFF_V  (2*NQf)
#define OFF_AW (3*NQf)
#define OFF_AS (4*NQf)
#define OFF_MW (5*NQf)
#define OFF_LW (5*NQf + NROW)
#define OFF_MS (5*NQf + 2*NROW)
#define OFF_LS (5*NQf + 3*NROW)

// ---------------------------------------------------------------------------
// Kernel 1: LayerNorm (per (b,l,h) over 64 dims) + QKV projection.
// One wave handles 8 tasks; weights transposed in LDS, each W float4 read
// amortized over 8 tasks. Q/K/V stored [B,H,L,64] for attention contiguity.
// ---------------------------------------------------------------------------
__global__ __launch_bounds__(256) void k1_ln_qkv(
    const float* __restrict__ x,  const float* __restrict__ Wq,
    const float* __restrict__ Wk, const float* __restrict__ Wv,
    const float* __restrict__ lns, const float* __restrict__ lnb,
    float* __restrict__ ws)
{
    __shared__ float WT[3][64][68];   // [proj][e][d] transposed
    __shared__ float hb[4][8][68];    // per-wave h rows

    const int tid = threadIdx.x;
    for (int idx = tid; idx < 3*64*64; idx += 256) {
        int p = idx >> 12, rem = idx & 4095, d = rem >> 6, e = rem & 63;
        const float* W = (p == 0) ? Wq : (p == 1) ? Wk : Wv;
        WT[p][e][d] = W[rem];
    }
    __syncthreads();

    const int w = tid >> 6, lane = tid & 63;
    const int base = blockIdx.x * 32 + w * 8;
    const float scl = lns[lane], bia = lnb[lane];

    for (int t = 0; t < 8; ++t) {
        int n = base + t;
        float xv = x[n*64 + lane];
        float s1 = xv, s2 = xv*xv;
        #pragma unroll
        for (int mk = 1; mk < 64; mk <<= 1) {
            s1 += __shfl_xor(s1, mk);
            s2 += __shfl_xor(s2, mk);
        }
        float mu  = s1 * (1.0f/64.0f);
        float var = s2 * (1.0f/64.0f) - mu*mu;
        float rs  = rsqrtf(var + 1e-5f);
        hb[w][t][lane] = (xv - mu) * rs * scl + bia;
    }
    __syncthreads();

    float aq[8] = {}, ak[8] = {}, av[8] = {};
    #pragma unroll
    for (int c = 0; c < 16; ++c) {
        float4 wq = *(const float4*)&WT[0][lane][4*c];
        float4 wk = *(const float4*)&WT[1][lane][4*c];
        float4 wv = *(const float4*)&WT[2][lane][4*c];
        #pragma unroll
        for (int t = 0; t < 8; ++t) {
            float4 h4 = *(const float4*)&hb[w][t][4*c];
            aq[t] = fmaf(h4.x,wq.x, fmaf(h4.y,wq.y, fmaf(h4.z,wq.z, fmaf(h4.w,wq.w, aq[t]))));
            ak[t] = fmaf(h4.x,wk.x, fmaf(h4.y,wk.y, fmaf(h4.z,wk.z, fmaf(h4.w,wk.w, ak[t]))));
            av[t] = fmaf(h4.x,wv.x, fmaf(h4.y,wv.y, fmaf(h4.z,wv.z, fmaf(h4.w,wv.w, av[t]))));
        }
    }

    for (int t = 0; t < 8; ++t) {
        int n = base + t;
        int b = n >> 14, l = (n >> 3) & 2047, h = n & 7;
        int off = ((b*8 + h)*Lq + l)*64 + lane;
        ws[OFF_Q + off] = aq[t];
        ws[OFF_K + off] = ak[t];
        ws[OFF_V + off] = av[t];
    }
}

// ---------------------------------------------------------------------------
// Kernel 2: strided attention partial. Workgroup = (bh, r). Queries i=r+64t,
// keys j=r+64s (s != t; j==i handled by window kernel). K/V/Q rows staged in
// LDS once, reused by all 32 queries. Outputs partial (m, l, acc).
// ---------------------------------------------------------------------------
__global__ __launch_bounds__(256) void k2_strided(float* __restrict__ ws)
{
    __shared__ float KS[32][68], VS[32][68], QG[32][68];
    __shared__ float PB[4][2][32];

    const int tid = threadIdx.x;
    const int bh = blockIdx.x >> 6, r = blockIdx.x & 63;
    const int Gbase = bh * Lq;

    for (int idx = tid; idx < 3*32*16; idx += 256) {
        int a = idx >> 9, rem = idx & 511, s = rem >> 4, c = rem & 15;
        int row = Gbase + r + 64*s;
        const float* src = ws + (a==0 ? OFF_K : a==1 ? OFF_V : OFF_Q) + row*64 + 4*c;
        float4 v = *(const float4*)src;
        float* dst = (a==0) ? &KS[s][4*c] : (a==1) ? &VS[s][4*c] : &QG[s][4*c];
        *(float4*)dst = v;
    }
    __syncthreads();

    const int w = tid >> 6, lane = tid & 63;
    const int sidx = lane & 31, half = lane >> 5;

    for (int p = 0; p < 4; ++p) {
        int t = w*8 + p*2 + half;           // query index 0..31, 2 per pass per wave
        float4 a4 = make_float4(0.f,0.f,0.f,0.f);
        #pragma unroll
        for (int c = 0; c < 16; ++c) {
            float4 kk = *(const float4*)&KS[sidx][4*c];
            float4 qq = *(const float4*)&QG[t][4*c];
            a4.x = fmaf(kk.x, qq.x, a4.x);
            a4.y = fmaf(kk.y, qq.y, a4.y);
            a4.z = fmaf(kk.z, qq.z, a4.z);
            a4.w = fmaf(kk.w, qq.w, a4.w);
        }
        float scv = (a4.x + a4.y + a4.z + a4.w) * 0.125f;
        if (sidx == t) scv = -1e30f;        // self handled by window kernel

        float m = scv;
        #pragma unroll
        for (int mk = 1; mk < 32; mk <<= 1) m = fmaxf(m, __shfl_xor(m, mk));
        float pe = __expf(scv - m);
        float lsum = pe;
        #pragma unroll
        for (int mk = 1; mk < 32; mk <<= 1) lsum += __shfl_xor(lsum, mk);

        PB[w][half][sidx] = pe;
        if (sidx == 0) {
            int i = r + 64*t;
            ws[OFF_MS + Gbase + i] = m;
            ws[OFF_LS + Gbase + i] = lsum;
        }

        float oa = 0.f, ob = 0.f;
        #pragma unroll
        for (int s = 0; s < 32; ++s) {
            float vv = VS[s][lane];
            oa = fmaf(PB[w][0][s], vv, oa);
            ob = fmaf(PB[w][1][s], vv, ob);
        }
        int ta = w*8 + p*2;
        int ra = (Gbase + r + 64*ta)*64 + lane;
        int rb = (Gbase + r + 64*(ta+1))*64 + lane;
        ws[OFF_AS + ra] = oa;
        ws[OFF_AS + rb] = ob;
    }
}

// ---------------------------------------------------------------------------
// Kernel 3: window attention partial. Workgroup = (bh, I) with 32 consecutive
// queries. Stages the 94-row K/V band + 32 Q rows in LDS. Lane = window key.
// ---------------------------------------------------------------------------
__global__ __launch_bounds__(256) void k3_window(float* __restrict__ ws)
{
    __shared__ float KL[94][68], VL[94][68], QL[32][68];
    __shared__ float PW[4][64];

    const int tid = threadIdx.x;
    const int bh = blockIdx.x >> 6, I = blockIdx.x & 63;
    const int qbase = I*32, j0 = qbase - 31;
    const int Gbase = bh * Lq;

    for (int idx = tid; idx < (94*2 + 32)*16; idx += 256) {
        int row = idx >> 4, c = idx & 15;
        if (row < 188) {
            int rr = (row < 94) ? row : row - 94;
            int j = j0 + rr;
            float4 v = make_float4(0.f,0.f,0.f,0.f);
            if (j >= 0 && j < Lq) {
                const float* src = ws + (row < 94 ? OFF_K : OFF_V) + (Gbase + j)*64 + 4*c;
                v = *(const float4*)src;
            }
            if (row < 94) *(float4*)&KL[rr][4*c] = v;
            else          *(float4*)&VL[rr][4*c] = v;
        } else {
            int rr = row - 188;
            float4 v = *(const float4*)(ws + OFF_Q + (Gbase + qbase + rr)*64 + 4*c);
            *(float4*)&QL[rr][4*c] = v;
        }
    }
    __syncthreads();

    const int w = tid >> 6, lane = tid & 63;

    for (int tt = 0; tt < 8; ++tt) {
        int t = w*8 + tt, i = qbase + t;
        int j = i - 31 + lane;                 // this lane's window key
        int rho = t + lane;
        int rhoc = (rho > 93) ? 93 : rho;      // lane 63 is masked anyway
        bool valid = (lane < 63) && (j >= 0) && (j < Lq);

        float4 a4 = make_float4(0.f,0.f,0.f,0.f);
        #pragma unroll
        for (int c = 0; c < 16; ++c) {
            float4 kk = *(const float4*)&KL[rhoc][4*c];
            float4 qq = *(const float4*)&QL[t][4*c];
            a4.x = fmaf(kk.x, qq.x, a4.x);
            a4.y = fmaf(kk.y, qq.y, a4.y);
            a4.z = fmaf(kk.z, qq.z, a4.z);
            a4.w = fmaf(kk.w, qq.w, a4.w);
        }
        float scv = (a4.x + a4.y + a4.z + a4.w) * 0.125f;
        scv = valid ? scv : -1e30f;

        float m = scv;
        #pragma unroll
        for (int mk = 1; mk < 64; mk <<= 1) m = fmaxf(m, __shfl_xor(m, mk));
        float pe = __expf(scv - m);
        float lsum = pe;
        #pragma unroll
        for (int mk = 1; mk < 64; mk <<= 1) lsum += __shfl_xor(lsum, mk);

        PW[w][lane] = pe;
        if (lane == 0) {
            ws[OFF_MW + Gbase + i] = m;
            ws[OFF_LW + Gbase + i] = lsum;
        }

        float o = 0.f;
        #pragma unroll
        for (int ww = 0; ww < 63; ++ww)
            o = fmaf(PW[w][ww], VL[t + ww][lane], o);
        ws[OFF_AW + (Gbase + i)*64 + lane] = o;
    }
}

// ---------------------------------------------------------------------------
// Kernel 4: merge window+strided partials, project through Wo, add residual.
// ---------------------------------------------------------------------------
__global__ __launch_bounds__(256) void k4_merge_out(
    const float* __restrict__ x, const float* __restrict__ Wo,
    const float* __restrict__ ws, float* __restrict__ out)
{
    __shared__ float WoT[64][68];
    __shared__ float ab[4][8][68];

    const int tid = threadIdx.x;
    for (int idx = tid; idx < 64*64; idx += 256) {
        int d = idx >> 6, e = idx & 63;
        WoT[e][d] = Wo[idx];
    }
    __syncthreads();

    const int w = tid >> 6, lane = tid & 63;
    const int base = blockIdx.x * 32 + w * 8;

    for (int t = 0; t < 8; ++t) {
        int n = base + t;
        int b = n >> 14, l = (n >> 3) & 2047, hh = n & 7;
        int row = (b*8 + hh)*Lq + l;
        float mw = ws[OFF_MW + row], lw = ws[OFF_LW + row];
        float msv = ws[OFF_MS + row], lsv = ws[OFF_LS + row];
        float m  = fmaxf(mw, msv);
        float ew = __expf(mw - m), es = __expf(msv - m);
        float inv = 1.0f / (lw*ew + lsv*es);
        int off = row*64 + lane;
        float a = (ws[OFF_AW + off]*ew + ws[OFF_AS + off]*es) * inv;
        ab[w][t][lane] = a;
    }
    __syncthreads();

    float acc[8] = {};
    #pragma unroll
    for (int c = 0; c < 16; ++c) {
        float4 wo4 = *(const float4*)&WoT[lane][4*c];
        #pragma unroll
        for (int t = 0; t < 8; ++t) {
            float4 a4 = *(const float4*)&ab[w][t][4*c];
            acc[t] = fmaf(a4.x,wo4.x, fmaf(a4.y,wo4.y, fmaf(a4.z,wo4.z, fmaf(a4.w,wo4.w, acc[t]))));
        }
    }
    for (int t = 0; t < 8; ++t) {
        int n = base + t;
        out[n*64 + lane] = acc[t] + x[n*64 + lane];
    }
}

// ---------------------------------------------------------------------------
extern "C" void kernel_launch(void* const* d_in, const int* in_sizes, int n_in,
                              void* d_out, int out_size, void* d_ws, size_t ws_size,
                              hipStream_t stream)
{
    const float* x   = (const float*)d_in[0];
    const float* Wq  = (const float*)d_in[1];
    const float* Wk  = (const float*)d_in[2];
    const float* Wv  = (const float*)d_in[3];
    const float* Wo  = (const float*)d_in[4];
    const float* lns = (const float*)d_in[5];
    const float* lnb = (const float*)d_in[6];
    float* ws  = (float*)d_ws;
    float* out = (float*)d_out;

    k1_ln_qkv  <<<dim3(1024), dim3(256), 0, stream>>>(x, Wq, Wk, Wv, lns, lnb, ws);
    k2_strided <<<dim3(1024), dim3(256), 0, stream>>>(ws);
    k3_window  <<<dim3(1024), dim3(256), 0, stream>>>(ws);
    k4_merge_out<<<dim3(1024), dim3(256), 0, stream>>>(x, Wo, ws, out);
}

// Round 2
// 58.490 us; speedup vs baseline: 1.6605x; 1.6605x over previous
//
#include <hip/hip_runtime.h>

typedef __attribute__((ext_vector_type(8))) short short8b;   // 8 x bf16 (4 VGPRs)
typedef __attribute__((ext_vector_type(4))) float float4a;   // 4 x f32 acc

#define Lq   2048
#define NQf  (16*2048*64)     // elements per [16][2048][64] array
#define NROW (16*2048)

__device__ inline unsigned short f2bf(float x){
    union{float f; unsigned u;} v; v.f = x;
    unsigned r = (v.u + 0x7fffu + ((v.u>>16)&1u))>>16;   // RNE
    return (unsigned short)r;
}

// ---------------------------------------------------------------------------
// Kernel 1: LayerNorm + QKV projection (f32 VALU), outputs bf16 Q/K/V
// laid out [B*H][L][64].
// ---------------------------------------------------------------------------
__global__ __launch_bounds__(256) void k1_ln_qkv(
    const float* __restrict__ x,  const float* __restrict__ Wq,
    const float* __restrict__ Wk, const float* __restrict__ Wv,
    const float* __restrict__ lns, const float* __restrict__ lnb,
    unsigned short* __restrict__ Qb, unsigned short* __restrict__ Kb,
    unsigned short* __restrict__ Vb)
{
    __shared__ float WT[3][64][68];   // [proj][e][d] transposed
    __shared__ float hb[4][8][68];    // per-wave h rows

    const int tid = threadIdx.x;
    for (int idx = tid; idx < 3*64*64; idx += 256) {
        int p = idx >> 12, rem = idx & 4095, d = rem >> 6, e = rem & 63;
        const float* W = (p == 0) ? Wq : (p == 1) ? Wk : Wv;
        WT[p][e][d] = W[rem];
        (void)d;
    }
    __syncthreads();

    const int w = tid >> 6, lane = tid & 63;
    const int base = blockIdx.x * 32 + w * 8;
    const float scl = lns[lane], bia = lnb[lane];

    for (int t = 0; t < 8; ++t) {
        int n = base + t;
        float xv = x[n*64 + lane];
        float s1 = xv, s2 = xv*xv;
        #pragma unroll
        for (int mk = 1; mk < 64; mk <<= 1) {
            s1 += __shfl_xor(s1, mk);
            s2 += __shfl_xor(s2, mk);
        }
        float mu  = s1 * (1.0f/64.0f);
        float var = s2 * (1.0f/64.0f) - mu*mu;
        float rs  = rsqrtf(var + 1e-5f);
        hb[w][t][lane] = (xv - mu) * rs * scl + bia;
    }
    __syncthreads();

    float aq[8] = {}, ak[8] = {}, av[8] = {};
    #pragma unroll
    for (int cc = 0; cc < 16; ++cc) {
        float4 wq = *(const float4*)&WT[0][lane][4*cc];
        float4 wk = *(const float4*)&WT[1][lane][4*cc];
        float4 wv = *(const float4*)&WT[2][lane][4*cc];
        #pragma unroll
        for (int t = 0; t < 8; ++t) {
            float4 h4 = *(const float4*)&hb[w][t][4*cc];
            aq[t] = fmaf(h4.x,wq.x, fmaf(h4.y,wq.y, fmaf(h4.z,wq.z, fmaf(h4.w,wq.w, aq[t]))));
            ak[t] = fmaf(h4.x,wk.x, fmaf(h4.y,wk.y, fmaf(h4.z,wk.z, fmaf(h4.w,wk.w, ak[t]))));
            av[t] = fmaf(h4.x,wv.x, fmaf(h4.y,wv.y, fmaf(h4.z,wv.z, fmaf(h4.w,wv.w, av[t]))));
        }
    }

    for (int t = 0; t < 8; ++t) {
        int n = base + t;
        int b = n >> 14, l = (n >> 3) & 2047, h = n & 7;
        int off = ((b*8 + h)*Lq + l)*64 + lane;
        Qb[off] = f2bf(aq[t]);
        Kb[off] = f2bf(ak[t]);
        Vb[off] = f2bf(av[t]);
    }
}

// ---------------------------------------------------------------------------
// Kernel 1b: transpose V [bh][L][64] -> VT [bh][64][L] (bf16)
// ---------------------------------------------------------------------------
__global__ __launch_bounds__(256) void k1b_transpose(
    const unsigned short* __restrict__ Vb, unsigned short* __restrict__ VTb)
{
    __shared__ unsigned short T[64][72];
    const int tid = threadIdx.x;
    const int bh = blockIdx.x >> 5, lt = blockIdx.x & 31, l0 = lt*64;

    #pragma unroll
    for (int i = 0; i < 2; ++i) {
        int u = tid + 256*i;            // 0..511
        int rr = u >> 3, cc = u & 7;
        *(uint4*)&T[rr][8*cc] = *(const uint4*)&Vb[(bh*Lq + l0 + rr)*64 + 8*cc];
    }
    __syncthreads();

    const int d = tid >> 2;
    #pragma unroll
    for (int i = 0; i < 2; ++i) {
        int cl = (tid & 3) + 4*i;       // 0..7
        unsigned v0 = T[8*cl+0][d], v1 = T[8*cl+1][d];
        unsigned v2 = T[8*cl+2][d], v3 = T[8*cl+3][d];
        unsigned v4 = T[8*cl+4][d], v5 = T[8*cl+5][d];
        unsigned v6 = T[8*cl+6][d], v7 = T[8*cl+7][d];
        uint4 pk;
        pk.x = v0 | (v1<<16); pk.y = v2 | (v3<<16);
        pk.z = v4 | (v5<<16); pk.w = v6 | (v7<<16);
        *(uint4*)&VTb[(bh*64 + d)*Lq + l0 + 8*cl] = pk;
    }
}

// ---------------------------------------------------------------------------
// Kernel 2: strided attention partial, MFMA. WG = (bh, r). 32 queries i=r+64t,
// 32 keys j=r+64s. S^T = Kg·Qg^T (swapped), P in LDS, O = P·(VgT)^T.
// ---------------------------------------------------------------------------
__global__ __launch_bounds__(256) void k2_strided(
    const unsigned short* __restrict__ Qb, const unsigned short* __restrict__ Kb,
    const unsigned short* __restrict__ Vb,
    float* __restrict__ AS, float* __restrict__ MS, float* __restrict__ LS)
{
    __shared__ unsigned short Kg[32][72], Qg[32][72];
    __shared__ unsigned short VgT[64][40], Pl2[32][40];

    const int tid = threadIdx.x;
    const int bh = blockIdx.x >> 6, r = blockIdx.x & 63;
    const int Gbase = bh * Lq;
    const int w = tid >> 6, lane = tid & 63;
    const int g = lane >> 4, c = lane & 15;

    if (w < 2) {
        #pragma unroll
        for (int i = 0; i < 4; ++i) {
            int u = tid + 128*i;            // 0..511
            int arr = u >> 8, rem = u & 255, s = rem >> 3, cc = rem & 7;
            const unsigned short* src = (arr ? Qb : Kb) + (Gbase + r + 64*s)*64 + 8*cc;
            if (arr) *(uint4*)&Qg[s][8*cc] = *(const uint4*)src;
            else     *(uint4*)&Kg[s][8*cc] = *(const uint4*)src;
        }
    } else {
        int s0 = 16*(w-2);
        unsigned short tmp[16];
        #pragma unroll
        for (int q = 0; q < 16; ++q)
            tmp[q] = Vb[(Gbase + r + 64*(s0+q))*64 + lane];
        uint4 p0, p1;
        p0.x = tmp[0] | ((unsigned)tmp[1]<<16);  p0.y = tmp[2] | ((unsigned)tmp[3]<<16);
        p0.z = tmp[4] | ((unsigned)tmp[5]<<16);  p0.w = tmp[6] | ((unsigned)tmp[7]<<16);
        p1.x = tmp[8] | ((unsigned)tmp[9]<<16);  p1.y = tmp[10]| ((unsigned)tmp[11]<<16);
        p1.z = tmp[12]| ((unsigned)tmp[13]<<16); p1.w = tmp[14]| ((unsigned)tmp[15]<<16);
        *(uint4*)&VgT[lane][s0]     = p0;
        *(uint4*)&VgT[lane][s0 + 8] = p1;
    }
    __syncthreads();

    if (w < 2) {
        const int tt = w, t_full = 16*tt + c;
        float4a sa0 = {0.f,0.f,0.f,0.f}, sa1 = {0.f,0.f,0.f,0.f};
        #pragma unroll
        for (int ks = 0; ks < 2; ++ks) {
            short8b bq = *(const short8b*)&Qg[t_full][32*ks + 8*g];
            short8b a0 = *(const short8b*)&Kg[c     ][32*ks + 8*g];
            short8b a1 = *(const short8b*)&Kg[16 + c][32*ks + 8*g];
            sa0 = __builtin_amdgcn_mfma_f32_16x16x32_bf16(a0, bq, sa0, 0,0,0);
            sa1 = __builtin_amdgcn_mfma_f32_16x16x32_bf16(a1, bq, sa1, 0,0,0);
        }
        float pv[8];
        float m = -1e30f;
        #pragma unroll
        for (int st = 0; st < 2; ++st) {
            #pragma unroll
            for (int rr = 0; rr < 4; ++rr) {
                int s_full = 16*st + 4*g + rr;
                float s = (s_full == t_full) ? -1e30f
                          : ((st ? sa1[rr] : sa0[rr]) * 0.125f);
                pv[4*st + rr] = s;
                m = fmaxf(m, s);
            }
        }
        m = fmaxf(m, __shfl_xor(m, 16));
        m = fmaxf(m, __shfl_xor(m, 32));
        float lsum = 0.f;
        #pragma unroll
        for (int q = 0; q < 8; ++q) { pv[q] = __expf(pv[q] - m); lsum += pv[q]; }
        lsum += __shfl_xor(lsum, 16);
        lsum += __shfl_xor(lsum, 32);
        #pragma unroll
        for (int st = 0; st < 2; ++st) {
            ushort4 pk;
            pk.x = f2bf(pv[4*st+0]); pk.y = f2bf(pv[4*st+1]);
            pk.z = f2bf(pv[4*st+2]); pk.w = f2bf(pv[4*st+3]);
            *(ushort4*)&Pl2[t_full][16*st + 4*g] = pk;
        }
        if (g == 0) {
            MS[Gbase + r + 64*t_full] = m;
            LS[Gbase + r + 64*t_full] = lsum;
        }
    }
    __syncthreads();

    const int mt = w & 1, nd0 = (w >> 1) * 2;
    short8b ap = *(const short8b*)&Pl2[16*mt + c][8*g];
    short8b b0 = *(const short8b*)&VgT[16*nd0 + c][8*g];
    short8b b1 = *(const short8b*)&VgT[16*(nd0+1) + c][8*g];
    float4a z = {0.f,0.f,0.f,0.f};
    float4a o0 = __builtin_amdgcn_mfma_f32_16x16x32_bf16(ap, b0, z, 0,0,0);
    float4a o1 = __builtin_amdgcn_mfma_f32_16x16x32_bf16(ap, b1, z, 0,0,0);
    #pragma unroll
    for (int rr = 0; rr < 4; ++rr) {
        int t_full = 16*mt + 4*g + rr;
        int rowoff = (Gbase + r + 64*t_full)*64;
        AS[rowoff + 16*nd0 + c]     = o0[rr];
        AS[rowoff + 16*(nd0+1) + c] = o1[rr];
    }
}

// ---------------------------------------------------------------------------
// Kernel 3: window attention partial, MFMA. WG = (bh, I): 32 queries, 96-row
// aligned K band j0=32I-32. S^T = K·Q^T (swapped); P in LDS; O = P·(VT)^T.
// ---------------------------------------------------------------------------
__global__ __launch_bounds__(256) void k3_window(
    const unsigned short* __restrict__ Qb, const unsigned short* __restrict__ Kb,
    const unsigned short* __restrict__ VTb,
    float* __restrict__ AW, float* __restrict__ MW, float* __restrict__ LW)
{
    __shared__ unsigned short Kl[96][72];
    __shared__ unsigned short Ql[32][72];
    __shared__ unsigned short VTl[64][104];
    __shared__ unsigned short Pl[32][104];

    const int tid = threadIdx.x;
    const int bh = blockIdx.x >> 6, I = blockIdx.x & 63;
    const int qbase = I*32, j0 = qbase - 32;
    const int Gbase = bh * Lq;

    #pragma unroll
    for (int i = 0; i < 4; ++i) {
        int u = tid + 256*i;               // 0..1023
        if (u < 768) {
            int rr = u >> 3, cc = u & 7;
            int j = j0 + rr; j = j < 0 ? 0 : (j > 2047 ? 2047 : j);
            *(uint4*)&Kl[rr][8*cc] = *(const uint4*)&Kb[(Gbase + j)*64 + 8*cc];
        } else {
            int uq = u - 768; int rr = uq >> 3, cc = uq & 7;
            *(uint4*)&Ql[rr][8*cc] = *(const uint4*)&Qb[(Gbase + qbase + rr)*64 + 8*cc];
        }
    }
    __syncthreads();

    const int w = tid >> 6, lane = tid & 63;
    const int g = lane >> 4, c = lane & 15;

    if (w < 2) {
        const int it = w, ti = 16*it + c;
        float4a acc[6];
        #pragma unroll
        for (int jt = 0; jt < 6; ++jt) acc[jt] = (float4a){0.f,0.f,0.f,0.f};
        #pragma unroll
        for (int ks = 0; ks < 2; ++ks) {
            short8b bq = *(const short8b*)&Ql[ti][32*ks + 8*g];
            #pragma unroll
            for (int jt = 0; jt < 6; ++jt) {
                short8b ak = *(const short8b*)&Kl[16*jt + c][32*ks + 8*g];
                acc[jt] = __builtin_amdgcn_mfma_f32_16x16x32_bf16(ak, bq, acc[jt], 0,0,0);
            }
        }
        float pv[24];
        float m = -1e30f;
        #pragma unroll
        for (int jt = 0; jt < 6; ++jt) {
            #pragma unroll
            for (int rr = 0; rr < 4; ++rr) {
                int jj = 16*jt + 4*g + rr;
                int jv = j0 + jj;
                bool valid = (jj > ti) && (jj < ti + 64) && (jv >= 0) && (jv < 2048);
                float s = valid ? acc[jt][rr]*0.125f : -1e30f;
                pv[4*jt + rr] = s;
                m = fmaxf(m, s);
            }
        }
        m = fmaxf(m, __shfl_xor(m, 16));
        m = fmaxf(m, __shfl_xor(m, 32));
        float lsum = 0.f;
        #pragma unroll
        for (int q = 0; q < 24; ++q) { pv[q] = __expf(pv[q] - m); lsum += pv[q]; }
        lsum += __shfl_xor(lsum, 16);
        lsum += __shfl_xor(lsum, 32);
        #pragma unroll
        for (int jt = 0; jt < 6; ++jt) {
            ushort4 pk;
            pk.x = f2bf(pv[4*jt+0]); pk.y = f2bf(pv[4*jt+1]);
            pk.z = f2bf(pv[4*jt+2]); pk.w = f2bf(pv[4*jt+3]);
            *(ushort4*)&Pl[ti][16*jt + 4*g] = pk;
        }
        if (g == 0) {
            MW[Gbase + qbase + ti] = m;
            LW[Gbase + qbase + ti] = lsum;
        }
    } else {
        int local = tid - 128;             // 0..127
        int d = local >> 1, half = local & 1;
        const unsigned short* vrow = VTb + (bh*64 + d)*Lq;
        #pragma unroll
        for (int q = 0; q < 6; ++q) {
            int cc = 6*half + q;
            int js = j0 + 8*cc;
            js = js < 0 ? 0 : (js > 2040 ? 2040 : js);
            *(uint4*)&VTl[d][8*cc] = *(const uint4*)&vrow[js];
        }
    }
    __syncthreads();

    const int mt = w & 1, nd0 = (w >> 1) * 2;
    float4a o0 = {0.f,0.f,0.f,0.f}, o1 = {0.f,0.f,0.f,0.f};
    #pragma unroll
    for (int ks = 0; ks < 3; ++ks) {
        short8b ap = *(const short8b*)&Pl[16*mt + c][32*ks + 8*g];
        short8b b0 = *(const short8b*)&VTl[16*nd0 + c][32*ks + 8*g];
        short8b b1 = *(const short8b*)&VTl[16*(nd0+1) + c][32*ks + 8*g];
        o0 = __builtin_amdgcn_mfma_f32_16x16x32_bf16(ap, b0, o0, 0,0,0);
        o1 = __builtin_amdgcn_mfma_f32_16x16x32_bf16(ap, b1, o1, 0,0,0);
    }
    #pragma unroll
    for (int rr = 0; rr < 4; ++rr) {
        int i = qbase + 16*mt + 4*g + rr;
        int rowoff = (Gbase + i)*64;
        AW[rowoff + 16*nd0 + c]     = o0[rr];
        AW[rowoff + 16*(nd0+1) + c] = o1[rr];
    }
}

// ---------------------------------------------------------------------------
// Kernel 4: merge window+strided partials, project through Wo, add residual.
// ---------------------------------------------------------------------------
__global__ __launch_bounds__(256) void k4_merge_out(
    const float* __restrict__ x, const float* __restrict__ Wo,
    const float* __restrict__ AW, const float* __restrict__ AS,
    const float* __restrict__ MW, const float* __restrict__ LW,
    const float* __restrict__ MS, const float* __restrict__ LS,
    float* __restrict__ out)
{
    __shared__ float WoT[64][68];
    __shared__ float ab[4][8][68];

    const int tid = threadIdx.x;
    for (int idx = tid; idx < 64*64; idx += 256) {
        int d = idx >> 6, e = idx & 63;
        WoT[e][d] = Wo[idx];
    }
    __syncthreads();

    const int w = tid >> 6, lane = tid & 63;
    const int base = blockIdx.x * 32 + w * 8;

    for (int t = 0; t < 8; ++t) {
        int n = base + t;
        int b = n >> 14, l = (n >> 3) & 2047, hh = n & 7;
        int row = (b*8 + hh)*Lq + l;
        float mw = MW[row], lw = LW[row];
        float msv = MS[row], lsv = LS[row];
        float m  = fmaxf(mw, msv);
        float ew = __expf(mw - m), es = __expf(msv - m);
        float inv = 1.0f / (lw*ew + lsv*es);
        int off = row*64 + lane;
        ab[w][t][lane] = (AW[off]*ew + AS[off]*es) * inv;
    }
    __syncthreads();

    float acc[8] = {};
    #pragma unroll
    for (int cc = 0; cc < 16; ++cc) {
        float4 wo4 = *(const float4*)&WoT[lane][4*cc];
        #pragma unroll
        for (int t = 0; t < 8; ++t) {
            float4 a4 = *(const float4*)&ab[w][t][4*cc];
            acc[t] = fmaf(a4.x,wo4.x, fmaf(a4.y,wo4.y, fmaf(a4.z,wo4.z, fmaf(a4.w,wo4.w, acc[t]))));
        }
    }
    for (int t = 0; t < 8; ++t) {
        int n = base + t;
        out[n*64 + lane] = acc[t] + x[n*64 + lane];
    }
}

// ---------------------------------------------------------------------------
extern "C" void kernel_launch(void* const* d_in, const int* in_sizes, int n_in,
                              void* d_out, int out_size, void* d_ws, size_t ws_size,
                              hipStream_t stream)
{
    const float* x   = (const float*)d_in[0];
    const float* Wq  = (const float*)d_in[1];
    const float* Wk  = (const float*)d_in[2];
    const float* Wv  = (const float*)d_in[3];
    const float* Wo  = (const float*)d_in[4];
    const float* lns = (const float*)d_in[5];
    const float* lnb = (const float*)d_in[6];
    float* out = (float*)d_out;

    unsigned short* Qb  = (unsigned short*)d_ws;
    unsigned short* Kb  = Qb + NQf;
    unsigned short* Vb  = Kb + NQf;
    unsigned short* VTb = Vb + NQf;
    float* AW = (float*)(VTb + NQf);
    float* AS = AW + NQf;
    float* MW = AS + NQf;
    float* LW = MW + NROW;
    float* MS = LW + NROW;
    float* LS = MS + NROW;

    k1_ln_qkv    <<<dim3(1024), dim3(256), 0, stream>>>(x, Wq, Wk, Wv, lns, lnb, Qb, Kb, Vb);
    k1b_transpose<<<dim3(512),  dim3(256), 0, stream>>>(Vb, VTb);
    k2_strided   <<<dim3(1024), dim3(256), 0, stream>>>(Qb, Kb, Vb, AS, MS, LS);
    k3_window    <<<dim3(1024), dim3(256), 0, stream>>>(Qb, Kb, VTb, AW, MW, LW);
    k4_merge_out <<<dim3(1024), dim3(256), 0, stream>>>(x, Wo, AW, AS, MW, LW, MS, LS, out);
}

// Round 3
// 42.416 us; speedup vs baseline: 2.2897x; 1.3790x over previous
//
#include <hip/hip_runtime.h>

typedef __attribute__((ext_vector_type(8))) short short8b;   // 8 x bf16 (4 VGPRs)
typedef __attribute__((ext_vector_type(4))) float float4a;   // 4 x f32 acc

#define Lq   2048
#define NQf  (16*2048*64)     // elements per [16][2048][64] array
#define NROW (16*2048)

__device__ inline unsigned short f2bf(float x){
    union{float f; unsigned u;} v; v.f = x;
    unsigned r = (v.u + 0x7fffu + ((v.u>>16)&1u))>>16;   // RNE
    return (unsigned short)r;
}
__device__ inline float bf2f(unsigned short u){
    union{unsigned u; float f;} v; v.u = ((unsigned)u)<<16;
    return v.f;
}

// ---------------------------------------------------------------------------
// Kernel 1: LayerNorm + QKV projection via MFMA. WG = 32 rows.
// h (bf16) staged in LDS; W^T (bf16) in LDS; out = h·W per projection.
// ---------------------------------------------------------------------------
__global__ __launch_bounds__(256) void k1_ln_qkv(
    const float* __restrict__ x,  const float* __restrict__ Wq,
    const float* __restrict__ Wk, const float* __restrict__ Wv,
    const float* __restrict__ lns, const float* __restrict__ lnb,
    unsigned short* __restrict__ Qb, unsigned short* __restrict__ Kb,
    unsigned short* __restrict__ Vb)
{
    __shared__ unsigned short WTl[3][64][72];   // [proj][e][d] = W[d][e]
    __shared__ unsigned short hl[32][72];

    const int tid = threadIdx.x;
    for (int idx = tid; idx < 3*4096; idx += 256) {
        int p = idx >> 12, rem = idx & 4095, d = rem >> 6, e = rem & 63;
        const float* W = (p==0)?Wq:(p==1)?Wk:Wv;
        WTl[p][e][d] = f2bf(W[rem]);
    }

    const int w = tid >> 6, lane = tid & 63;
    const int base = blockIdx.x * 32;
    const float scl = lns[lane], bia = lnb[lane];

    #pragma unroll
    for (int t = 0; t < 8; ++t) {
        int n = base + w*8 + t;
        float xv = x[n*64 + lane];
        float s1 = xv, s2 = xv*xv;
        #pragma unroll
        for (int mk = 1; mk < 64; mk <<= 1) {
            s1 += __shfl_xor(s1, mk);
            s2 += __shfl_xor(s2, mk);
        }
        float mu  = s1 * (1.0f/64.0f);
        float var = s2 * (1.0f/64.0f) - mu*mu;
        float rs  = rsqrtf(var + 1e-5f);
        hl[w*8 + t][lane] = f2bf((xv - mu)*rs*scl + bia);
    }
    __syncthreads();

    const int g = lane >> 4, c = lane & 15;
    #pragma unroll
    for (int ti = 0; ti < 6; ++ti) {
        int tau = w*6 + ti;                  // 24 tiles: p*8 + mt*4 + ne
        int p = tau >> 3, mt = (tau >> 2) & 1, ne = tau & 3;
        float4a acc = {0.f,0.f,0.f,0.f};
        #pragma unroll
        for (int ks = 0; ks < 2; ++ks) {
            short8b a = *(const short8b*)&hl[16*mt + c][32*ks + 8*g];
            short8b b = *(const short8b*)&WTl[p][16*ne + c][32*ks + 8*g];
            acc = __builtin_amdgcn_mfma_f32_16x16x32_bf16(a, b, acc, 0,0,0);
        }
        unsigned short* dst = (p==0)?Qb:(p==1)?Kb:Vb;
        #pragma unroll
        for (int rr = 0; rr < 4; ++rr) {
            int tl = 16*mt + 4*g + rr;
            int n = base + tl;
            int b_ = n >> 14, l = (n >> 3) & 2047, h = n & 7;
            dst[((b_*8 + h)*Lq + l)*64 + 16*ne + c] = f2bf(acc[rr]);
        }
    }
}

// ---------------------------------------------------------------------------
// Kernel 2+3 fused: strided (even blocks) / window (odd blocks) attention
// partials. Outputs bf16 O-partials + f32 m/l per row.
// ---------------------------------------------------------------------------
__global__ __launch_bounds__(256) void k23_attn(
    const unsigned short* __restrict__ Qb, const unsigned short* __restrict__ Kb,
    const unsigned short* __restrict__ Vb,
    unsigned short* __restrict__ AWb, unsigned short* __restrict__ ASb,
    float* __restrict__ MW, float* __restrict__ LW,
    float* __restrict__ MS, float* __restrict__ LS)
{
    __shared__ union {
        struct { unsigned short Kg[32][72], Qg[32][72], VgT[64][40], P[32][40]; } s;
        struct { unsigned short Kl[96][72], Ql[32][72], VTl[64][104], P[32][104]; } wd;
    } u;

    const int tid = threadIdx.x;
    const int w = tid >> 6, lane = tid & 63;
    const int g = lane >> 4, c = lane & 15;
    const int which = blockIdx.x & 1;
    const int bidx = blockIdx.x >> 1;       // 0..1023
    const int bh = bidx >> 6;
    const int Gbase = bh * Lq;

    if (which == 0) {
        // ================= strided =================
        const int r = bidx & 63;

        if (w < 2) {
            #pragma unroll
            for (int i = 0; i < 4; ++i) {
                int uu = tid + 128*i;            // 0..511
                int arr = uu >> 8, rem = uu & 255, s = rem >> 3, cc = rem & 7;
                const unsigned short* src = (arr ? Qb : Kb) + (Gbase + r + 64*s)*64 + 8*cc;
                if (arr) *(uint4*)&u.s.Qg[s][8*cc] = *(const uint4*)src;
                else     *(uint4*)&u.s.Kg[s][8*cc] = *(const uint4*)src;
            }
        } else {
            int s0 = 16*(w-2);
            unsigned short tmp[16];
            #pragma unroll
            for (int q = 0; q < 16; ++q)
                tmp[q] = Vb[(Gbase + r + 64*(s0+q))*64 + lane];
            uint4 p0, p1;
            p0.x = tmp[0] | ((unsigned)tmp[1]<<16);  p0.y = tmp[2] | ((unsigned)tmp[3]<<16);
            p0.z = tmp[4] | ((unsigned)tmp[5]<<16);  p0.w = tmp[6] | ((unsigned)tmp[7]<<16);
            p1.x = tmp[8] | ((unsigned)tmp[9]<<16);  p1.y = tmp[10]| ((unsigned)tmp[11]<<16);
            p1.z = tmp[12]| ((unsigned)tmp[13]<<16); p1.w = tmp[14]| ((unsigned)tmp[15]<<16);
            *(uint4*)&u.s.VgT[lane][s0]     = p0;
            *(uint4*)&u.s.VgT[lane][s0 + 8] = p1;
        }
        __syncthreads();

        if (w < 2) {
            const int t_full = 16*w + c;
            float4a sa0 = {0.f,0.f,0.f,0.f}, sa1 = {0.f,0.f,0.f,0.f};
            #pragma unroll
            for (int ks = 0; ks < 2; ++ks) {
                short8b bq = *(const short8b*)&u.s.Qg[t_full][32*ks + 8*g];
                short8b a0 = *(const short8b*)&u.s.Kg[c     ][32*ks + 8*g];
                short8b a1 = *(const short8b*)&u.s.Kg[16 + c][32*ks + 8*g];
                sa0 = __builtin_amdgcn_mfma_f32_16x16x32_bf16(a0, bq, sa0, 0,0,0);
                sa1 = __builtin_amdgcn_mfma_f32_16x16x32_bf16(a1, bq, sa1, 0,0,0);
            }
            float pv[8];
            float m = -1e30f;
            #pragma unroll
            for (int st = 0; st < 2; ++st) {
                #pragma unroll
                for (int rr = 0; rr < 4; ++rr) {
                    int s_full = 16*st + 4*g + rr;
                    float s = (s_full == t_full) ? -1e30f
                              : ((st ? sa1[rr] : sa0[rr]) * 0.125f);
                    pv[4*st + rr] = s;
                    m = fmaxf(m, s);
                }
            }
            m = fmaxf(m, __shfl_xor(m, 16));
            m = fmaxf(m, __shfl_xor(m, 32));
            float lsum = 0.f;
            #pragma unroll
            for (int q = 0; q < 8; ++q) { pv[q] = __expf(pv[q] - m); lsum += pv[q]; }
            lsum += __shfl_xor(lsum, 16);
            lsum += __shfl_xor(lsum, 32);
            #pragma unroll
            for (int st = 0; st < 2; ++st) {
                ushort4 pk;
                pk.x = f2bf(pv[4*st+0]); pk.y = f2bf(pv[4*st+1]);
                pk.z = f2bf(pv[4*st+2]); pk.w = f2bf(pv[4*st+3]);
                *(ushort4*)&u.s.P[t_full][16*st + 4*g] = pk;
            }
            if (g == 0) {
                MS[Gbase + r + 64*t_full] = m;
                LS[Gbase + r + 64*t_full] = lsum;
            }
        }
        __syncthreads();

        const int mt = w & 1, nd0 = (w >> 1) * 2;
        short8b ap = *(const short8b*)&u.s.P[16*mt + c][8*g];
        short8b b0 = *(const short8b*)&u.s.VgT[16*nd0 + c][8*g];
        short8b b1 = *(const short8b*)&u.s.VgT[16*(nd0+1) + c][8*g];
        float4a z = {0.f,0.f,0.f,0.f};
        float4a o0 = __builtin_amdgcn_mfma_f32_16x16x32_bf16(ap, b0, z, 0,0,0);
        float4a o1 = __builtin_amdgcn_mfma_f32_16x16x32_bf16(ap, b1, z, 0,0,0);
        #pragma unroll
        for (int rr = 0; rr < 4; ++rr) {
            int t_full = 16*mt + 4*g + rr;
            int rowoff = (Gbase + r + 64*t_full)*64;
            ASb[rowoff + 16*nd0 + c]     = f2bf(o0[rr]);
            ASb[rowoff + 16*(nd0+1) + c] = f2bf(o1[rr]);
        }
    } else {
        // ================= window =================
        const int I = bidx & 63;
        const int qbase = I*32, j0 = qbase - 32;

        #pragma unroll
        for (int i = 0; i < 4; ++i) {
            int uu = tid + 256*i;               // 0..1023
            if (uu < 768) {
                int rr = uu >> 3, cc = uu & 7;
                int j = j0 + rr; j = j < 0 ? 0 : (j > 2047 ? 2047 : j);
                *(uint4*)&u.wd.Kl[rr][8*cc] = *(const uint4*)&Kb[(Gbase + j)*64 + 8*cc];
            } else {
                int uq = uu - 768; int rr = uq >> 3, cc = uq & 7;
                *(uint4*)&u.wd.Ql[rr][8*cc] = *(const uint4*)&Qb[(Gbase + qbase + rr)*64 + 8*cc];
            }
        }
        __syncthreads();

        if (w < 2) {
            const int ti = 16*w + c;
            float4a acc[6];
            #pragma unroll
            for (int jt = 0; jt < 6; ++jt) acc[jt] = (float4a){0.f,0.f,0.f,0.f};
            #pragma unroll
            for (int ks = 0; ks < 2; ++ks) {
                short8b bq = *(const short8b*)&u.wd.Ql[ti][32*ks + 8*g];
                #pragma unroll
                for (int jt = 0; jt < 6; ++jt) {
                    short8b ak = *(const short8b*)&u.wd.Kl[16*jt + c][32*ks + 8*g];
                    acc[jt] = __builtin_amdgcn_mfma_f32_16x16x32_bf16(ak, bq, acc[jt], 0,0,0);
                }
            }
            float pv[24];
            float m = -1e30f;
            #pragma unroll
            for (int jt = 0; jt < 6; ++jt) {
                #pragma unroll
                for (int rr = 0; rr < 4; ++rr) {
                    int jj = 16*jt + 4*g + rr;
                    int jv = j0 + jj;
                    bool valid = (jj > ti) && (jj < ti + 64) && (jv >= 0) && (jv < 2048);
                    float s = valid ? acc[jt][rr]*0.125f : -1e30f;
                    pv[4*jt + rr] = s;
                    m = fmaxf(m, s);
                }
            }
            m = fmaxf(m, __shfl_xor(m, 16));
            m = fmaxf(m, __shfl_xor(m, 32));
            float lsum = 0.f;
            #pragma unroll
            for (int q = 0; q < 24; ++q) { pv[q] = __expf(pv[q] - m); lsum += pv[q]; }
            lsum += __shfl_xor(lsum, 16);
            lsum += __shfl_xor(lsum, 32);
            #pragma unroll
            for (int jt = 0; jt < 6; ++jt) {
                ushort4 pk;
                pk.x = f2bf(pv[4*jt+0]); pk.y = f2bf(pv[4*jt+1]);
                pk.z = f2bf(pv[4*jt+2]); pk.w = f2bf(pv[4*jt+3]);
                *(ushort4*)&u.wd.P[ti][16*jt + 4*g] = pk;
            }
            if (g == 0) {
                MW[Gbase + qbase + ti] = m;
                LW[Gbase + qbase + ti] = lsum;
            }
        } else {
            // build V^T tile from Vb rows: lane = d, 48 rows per wave
            const int w2 = w - 2;
            #pragma unroll
            for (int q8 = 0; q8 < 6; ++q8) {
                unsigned short v[8];
                #pragma unroll
                for (int q = 0; q < 8; ++q) {
                    int j = j0 + 48*w2 + 8*q8 + q;
                    j = j < 0 ? 0 : (j > 2047 ? 2047 : j);
                    v[q] = Vb[(Gbase + j)*64 + lane];
                }
                uint4 pk;
                pk.x = v[0] | ((unsigned)v[1]<<16);
                pk.y = v[2] | ((unsigned)v[3]<<16);
                pk.z = v[4] | ((unsigned)v[5]<<16);
                pk.w = v[6] | ((unsigned)v[7]<<16);
                *(uint4*)&u.wd.VTl[lane][48*w2 + 8*q8] = pk;
            }
        }
        __syncthreads();

        const int mt = w & 1, nd0 = (w >> 1) * 2;
        float4a o0 = {0.f,0.f,0.f,0.f}, o1 = {0.f,0.f,0.f,0.f};
        #pragma unroll
        for (int ks = 0; ks < 3; ++ks) {
            short8b ap = *(const short8b*)&u.wd.P[16*mt + c][32*ks + 8*g];
            short8b b0 = *(const short8b*)&u.wd.VTl[16*nd0 + c][32*ks + 8*g];
            short8b b1 = *(const short8b*)&u.wd.VTl[16*(nd0+1) + c][32*ks + 8*g];
            o0 = __builtin_amdgcn_mfma_f32_16x16x32_bf16(ap, b0, o0, 0,0,0);
            o1 = __builtin_amdgcn_mfma_f32_16x16x32_bf16(ap, b1, o1, 0,0,0);
        }
        #pragma unroll
        for (int rr = 0; rr < 4; ++rr) {
            int i = qbase + 16*mt + 4*g + rr;
            int rowoff = (Gbase + i)*64;
            AWb[rowoff + 16*nd0 + c]     = f2bf(o0[rr]);
            AWb[rowoff + 16*(nd0+1) + c] = f2bf(o1[rr]);
        }
    }
}

// ---------------------------------------------------------------------------
// Kernel 4: merge partials -> bf16 a; Wo projection via MFMA; +residual.
// ---------------------------------------------------------------------------
__global__ __launch_bounds__(256) void k4_merge_out(
    const float* __restrict__ x, const float* __restrict__ Wo,
    const unsigned short* __restrict__ AWb, const unsigned short* __restrict__ ASb,
    const float* __restrict__ MW, const float* __restrict__ LW,
    const float* __restrict__ MS, const float* __restrict__ LS,
    float* __restrict__ out)
{
    __shared__ unsigned short WoTl[64][72];    // [e][d] = Wo[d][e]
    __shared__ unsigned short Al[32][72];

    const int tid = threadIdx.x;
    for (int idx = tid; idx < 4096; idx += 256) {
        int d = idx >> 6, e = idx & 63;
        WoTl[e][d] = f2bf(Wo[idx]);
    }

    const int w = tid >> 6, lane = tid & 63;
    const int base = blockIdx.x * 32;

    #pragma unroll
    for (int t = 0; t < 8; ++t) {
        int tl = w*8 + t;
        int n = base + tl;
        int b = n >> 14, l = (n >> 3) & 2047, hh = n & 7;
        int row = (b*8 + hh)*Lq + l;
        float mw = MW[row], lw = LW[row];
        float msv = MS[row], lsv = LS[row];
        float m  = fmaxf(mw, msv);
        float ew = __expf(mw - m), es = __expf(msv - m);
        float inv = 1.0f / (lw*ew + lsv*es);
        int off = row*64 + lane;
        float a = (bf2f(AWb[off])*ew + bf2f(ASb[off])*es) * inv;
        Al[tl][lane] = f2bf(a);
    }
    __syncthreads();

    const int g = lane >> 4, c = lane & 15;
    #pragma unroll
    for (int ti = 0; ti < 2; ++ti) {
        int tau = w*2 + ti;                  // 8 tiles: mt*4 + ne
        int mt = tau >> 2, ne = tau & 3;
        float4a acc = {0.f,0.f,0.f,0.f};
        #pragma unroll
        for (int ks = 0; ks < 2; ++ks) {
            short8b a = *(const short8b*)&Al[16*mt + c][32*ks + 8*g];
            short8b b = *(const short8b*)&WoTl[16*ne + c][32*ks + 8*g];
            acc = __builtin_amdgcn_mfma_f32_16x16x32_bf16(a, b, acc, 0,0,0);
        }
        #pragma unroll
        for (int rr = 0; rr < 4; ++rr) {
            int tl = 16*mt + 4*g + rr;
            int n = base + tl;
            int col = 16*ne + c;
            out[n*64 + col] = acc[rr] + x[n*64 + col];
        }
    }
}

// ---------------------------------------------------------------------------
extern "C" void kernel_launch(void* const* d_in, const int* in_sizes, int n_in,
                              void* d_out, int out_size, void* d_ws, size_t ws_size,
                              hipStream_t stream)
{
    const float* x   = (const float*)d_in[0];
    const float* Wq  = (const float*)d_in[1];
    const float* Wk  = (const float*)d_in[2];
    const float* Wv  = (const float*)d_in[3];
    const float* Wo  = (const float*)d_in[4];
    const float* lns = (const float*)d_in[5];
    const float* lnb = (const float*)d_in[6];
    float* out = (float*)d_out;

    unsigned short* Qb  = (unsigned short*)d_ws;
    unsigned short* Kb  = Qb + NQf;
    unsigned short* Vb  = Kb + NQf;
    unsigned short* AWb = Vb + NQf;
    unsigned short* ASb = AWb + NQf;
    float* MW = (float*)(ASb + NQf);
    float* LW = MW + NROW;
    float* MS = LW + NROW;
    float* LS = MS + NROW;

    k1_ln_qkv   <<<dim3(1024), dim3(256), 0, stream>>>(x, Wq, Wk, Wv, lns, lnb, Qb, Kb, Vb);
    k23_attn    <<<dim3(2048), dim3(256), 0, stream>>>(Qb, Kb, Vb, AWb, ASb, MW, LW, MS, LS);
    k4_merge_out<<<dim3(1024), dim3(256), 0, stream>>>(x, Wo, AWb, ASb, MW, LW, MS, LS, out);
}